// Round 1
// baseline (3259.241 us; speedup 1.0000x reference)
//
#include <hip/hip_runtime.h>

#define NN      50000
#define NEDGE   1600000
#define NA      1000000
#define FEATD   128
#define EMBD    64
#define MAXSEND 50
#define WSTR    136   // padded LDS row stride in shorts (128 + 8)

typedef __attribute__((ext_vector_type(4))) float  f32x4;
typedef __attribute__((ext_vector_type(8))) __bf16 bf16x8;
typedef __attribute__((ext_vector_type(8))) short  s16x8;

__device__ __forceinline__ short f2bf(float f) {
    union { float f; unsigned u; } v; v.f = f;
    unsigned r = (v.u + 0x7fffu + ((v.u >> 16) & 1u)) >> 16;  // RNE
    return (short)r;
}

// ---------------- degree / norm ----------------
__global__ void k_count(const int* __restrict__ col, int* __restrict__ cnt) {
    int e = blockIdx.x * 256 + threadIdx.x;
    if (e < NEDGE) atomicAdd(&cnt[col[e]], 1);
}

__global__ void k_dinv(const int* __restrict__ cnt, float* __restrict__ dinv) {
    int v = blockIdx.x * 256 + threadIdx.x;
    if (v < NN) dinv[v] = rsqrtf((float)(cnt[v] + 1));  // +1 self loop; always >= 1
}

// ---------------- node GEMM: H[v][j] = sum_k X[v][k] W[k][j], j in [0,64) ----------------
template <int K>
__global__ void k_gemm_nodes(const float* __restrict__ X, const float* __restrict__ W,
                             float* __restrict__ H) {
    int wid  = (blockIdx.x * 256 + threadIdx.x) >> 6;  // one wave per node row
    int lane = threadIdx.x & 63;
    const float* xr = X + (long)wid * K;
    float x0 = xr[lane];
    float x1 = (K == 128) ? xr[lane + 64] : 0.f;
    float acc = 0.f;
#pragma unroll
    for (int k = 0; k < 64; k++) {
        float xv = __shfl(x0, k, 64);
        acc = fmaf(xv, W[k * EMBD + lane], acc);
    }
    if (K == 128) {
#pragma unroll
        for (int k = 0; k < 64; k++) {
            float xv = __shfl(x1, k, 64);
            acc = fmaf(xv, W[(k + 64) * EMBD + lane], acc);
        }
    }
    H[(long)wid * EMBD + lane] = acc;
}

// ---------------- edge scatter: acc[c] += H[r] * dinv[r]*dinv[c] ----------------
__global__ void k_scatter(const float* __restrict__ H, float* __restrict__ acc,
                          const int* __restrict__ row, const int* __restrict__ col,
                          const float* __restrict__ dinv) {
    long t = (long)blockIdx.x * 256 + threadIdx.x;
    long e = t >> 4;
    if (e >= NEDGE) return;
    int f4 = (int)(t & 15);
    int r = row[e], c = col[e];
    float nrm = dinv[r] * dinv[c];
    float4 v = ((const float4*)(H + (long)r * EMBD))[f4];
    float* dst = acc + (long)c * EMBD + f4 * 4;
    atomicAdd(dst + 0, v.x * nrm);
    atomicAdd(dst + 1, v.y * nrm);
    atomicAdd(dst + 2, v.z * nrm);
    atomicAdd(dst + 3, v.w * nrm);
}

// ---------------- finalize: out = (acc + H*dinv^2 + b), optional relu ----------------
__global__ void k_finalize(const float* __restrict__ acc, const float* __restrict__ H,
                           const float* __restrict__ dinv, const float* __restrict__ b,
                           float* __restrict__ out, int relu) {
    int t = blockIdx.x * 256 + threadIdx.x;
    if (t >= NN * 16) return;
    int v = t >> 4, f4 = t & 15;
    float d = dinv[v], d2 = d * d;
    float4 a = ((const float4*)acc)[t];
    float4 h = ((const float4*)H)[t];
    float4 bb = ((const float4*)b)[f4];
    float4 o;
    o.x = a.x + h.x * d2 + bb.x;
    o.y = a.y + h.y * d2 + bb.y;
    o.z = a.z + h.z * d2 + bb.z;
    o.w = a.w + h.w * d2 + bb.w;
    if (relu) {
        o.x = fmaxf(o.x, 0.f); o.y = fmaxf(o.y, 0.f);
        o.z = fmaxf(o.z, 0.f); o.w = fmaxf(o.w, 0.f);
    }
    ((float4*)out)[t] = o;
}

// ---------------- placement head: one wave per node ----------------
__global__ void k_placement(const float* __restrict__ emb, const float* __restrict__ Wp1,
                            const float* __restrict__ bp1, const float* __restrict__ Wp2,
                            const float* __restrict__ bp2, float* __restrict__ out) {
    int wid  = (blockIdx.x * 256 + threadIdx.x) >> 6;
    int lane = threadIdx.x & 63;
    float e0 = emb[(long)wid * EMBD + lane];
    float acc = 0.f;
#pragma unroll
    for (int k = 0; k < 64; k++) {
        float ev = __shfl(e0, k, 64);
        acc = fmaf(ev, Wp1[k * 64 + lane], acc);
    }
    acc = fmaxf(acc + bp1[lane], 0.f) * Wp2[lane];
#pragma unroll
    for (int off = 32; off; off >>= 1) acc += __shfl_xor(acc, off, 64);
    if (lane == 0) out[wid] = acc + bp2[0];
}

// ---------------- weight prep: bf16 transposed [n][k], n: 0-63 We1, 64-191 Wa1, 192-255 Wa2(pad) --
__global__ void k_prep(const float* __restrict__ We1, const float* __restrict__ Wa1,
                       const float* __restrict__ Wa2, short* __restrict__ Wt) {
    int t = blockIdx.x * 256 + threadIdx.x;
    if (t >= 256 * 128) return;
    int n = t >> 7, k = t & 127;
    float v;
    if (n < 64)       v = We1[k * 64 + n];
    else if (n < 192) v = Wa1[k * 128 + (n - 64)];
    else { int n2 = n - 192; v = (n2 < MAXSEND) ? Wa2[k * MAXSEND + n2] : 0.f; }
    Wt[t] = f2bf(v);
}

// ---------------- action-edge MLP: bf16 MFMA, one 16-action m-tile per wave ----------------
__launch_bounds__(512, 1)
__global__ void k_action(const float* __restrict__ emb, const int* __restrict__ ae,
                         const int* __restrict__ army, const short* __restrict__ Wt,
                         const float* __restrict__ be1, const float* __restrict__ We2,
                         const float* __restrict__ be2, const float* __restrict__ ba1,
                         const float* __restrict__ ba2,
                         float* __restrict__ out_edge, float* __restrict__ out_army) {
    extern __shared__ short lds[];
    int tid = threadIdx.x;
    // stage all weights into padded LDS (rows 0..255, stride WSTR shorts)
    for (int i = tid; i < 4096; i += 512) {
        int rw = i >> 4, c8 = (i & 15) * 8;
        *(uint4*)(lds + rw * WSTR + c8) = *(const uint4*)(Wt + rw * 128 + c8);
    }
    __syncthreads();

    int w = tid >> 6, lane = tid & 63;
    int m = lane & 15, q = lane >> 4;   // MFMA lane decomposition
    short* a1s = lds + 256 * WSTR + w * 16 * WSTR;  // per-wave 16x136 bf16 scratch

    float be1v[4], w2v[4], ba1v[8], ba2v[4];
#pragma unroll
    for (int t = 0; t < 4; t++) { be1v[t] = be1[t * 16 + m]; w2v[t] = We2[t * 16 + m]; }
#pragma unroll
    for (int t = 0; t < 8; t++) ba1v[t] = ba1[t * 16 + m];
#pragma unroll
    for (int nt = 0; nt < 4; nt++) { int n = nt * 16 + m; ba2v[nt] = (n < MAXSEND) ? ba2[n] : 0.f; }
    float be2v = be2[0];
    const f32x4 zero = {0.f, 0.f, 0.f, 0.f};

    int gw = blockIdx.x * 8 + w;
    int nwaves = gridDim.x * 8;
    for (int tile = gw; tile < NA / 16; tile += nwaves) {
        int a0 = tile * 16;
        // A-fragments: lane holds EE[a0+m][kk*32 + q*8 + j], EE = concat(emb[src], emb[tgt])
        int2 st = ((const int2*)ae)[a0 + m];
        s16x8 af[4];
#pragma unroll
        for (int kk = 0; kk < 4; kk++) {
            const float* base = (kk < 2) ? (emb + (long)st.x * 64 + kk * 32 + q * 8)
                                         : (emb + (long)st.y * 64 + (kk - 2) * 32 + q * 8);
            float4 u0 = *(const float4*)(base);
            float4 u1 = *(const float4*)(base + 4);
            s16x8 f;
            f[0] = f2bf(u0.x); f[1] = f2bf(u0.y); f[2] = f2bf(u0.z); f[3] = f2bf(u0.w);
            f[4] = f2bf(u1.x); f[5] = f2bf(u1.y); f[6] = f2bf(u1.z); f[7] = f2bf(u1.w);
            af[kk] = f;
        }
        // stage 1: n-tiles 0..3 -> e1 (We1 rows 0..63), 4..11 -> a1 (Wa1 rows 64..191)
        f32x4 acc[12];
#pragma unroll
        for (int t = 0; t < 12; t++) acc[t] = zero;
#pragma unroll
        for (int t = 0; t < 12; t++) {
#pragma unroll
            for (int kk = 0; kk < 4; kk++) {
                s16x8 bfrag = *(const s16x8*)(lds + (t * 16 + m) * WSTR + kk * 32 + q * 8);
                acc[t] = __builtin_amdgcn_mfma_f32_16x16x32_bf16(
                    __builtin_bit_cast(bf16x8, af[kk]),
                    __builtin_bit_cast(bf16x8, bfrag), acc[t], 0, 0, 0);
            }
        }
        // e1 epilogue -> edge-logit partials (C layout: row a=q*4+r, col j=t*16+m)
        float elp[4] = {0.f, 0.f, 0.f, 0.f};
#pragma unroll
        for (int t = 0; t < 4; t++) {
#pragma unroll
            for (int r = 0; r < 4; r++) {
                float v = fmaxf(acc[t][r] + be1v[t], 0.f);
                elp[r] = fmaf(v, w2v[t], elp[r]);
            }
        }
        // a1 epilogue -> bf16 into per-wave LDS scratch (row-major [16][WSTR])
#pragma unroll
        for (int t = 4; t < 12; t++) {
#pragma unroll
            for (int r = 0; r < 4; r++) {
                float v = fmaxf(acc[t][r] + ba1v[t - 4], 0.f);
                a1s[(q * 4 + r) * WSTR + (t - 4) * 16 + m] = f2bf(v);
            }
        }
        // reduce edge logits over the 16 j-lanes in each quad
#pragma unroll
        for (int r = 0; r < 4; r++) {
            float s = elp[r];
            s += __shfl_xor(s, 1, 64);
            s += __shfl_xor(s, 2, 64);
            s += __shfl_xor(s, 4, 64);
            s += __shfl_xor(s, 8, 64);
            elp[r] = s;
        }
        if (m == 0) {
#pragma unroll
            for (int r = 0; r < 4; r++) {
                int aa = a0 + q * 4 + r;
                int2 st2 = ((const int2*)ae)[aa];
                int sa = army[st2.x], ta = army[st2.y];
                float adj = ((sa <= 2) || (ta >= 3 * sa)) ? 1.f : 0.f;
                if (st2.x == st2.y) adj += 100.f;
                out_edge[aa] = elp[r] + be2v - adj;
            }
        }
        // src army counts for masking (rows a=q*4+r)
        int sa_loc[4];
#pragma unroll
        for (int r = 0; r < 4; r++) {
            int aa = a0 + q * 4 + r;
            sa_loc[r] = army[((const int2*)ae)[aa].x];
        }
        __asm__ volatile("s_waitcnt lgkmcnt(0)" ::: "memory");  // a1s writes -> reads
        // stage 2: army = relu(a1) @ Wa2 (rows 192..255 in LDS, cols padded to 64)
        s16x8 a2[4];
#pragma unroll
        for (int kk = 0; kk < 4; kk++)
            a2[kk] = *(const s16x8*)(a1s + m * WSTR + kk * 32 + q * 8);
#pragma unroll
        for (int nt = 0; nt < 4; nt++) {
            f32x4 c2 = zero;
#pragma unroll
            for (int kk = 0; kk < 4; kk++) {
                s16x8 bfrag = *(const s16x8*)(lds + (192 + nt * 16 + m) * WSTR + kk * 32 + q * 8);
                c2 = __builtin_amdgcn_mfma_f32_16x16x32_bf16(
                    __builtin_bit_cast(bf16x8, a2[kk]),
                    __builtin_bit_cast(bf16x8, bfrag), c2, 0, 0, 0);
            }
            int n = nt * 16 + m;
            if (n < MAXSEND) {
#pragma unroll
                for (int r = 0; r < 4; r++) {
                    int aa = a0 + q * 4 + r;
                    float v = c2[r] + ba2v[nt];
                    out_army[(long)aa * MAXSEND + n] = (n < sa_loc[r]) ? v : -1e9f;
                }
            }
        }
    }
}

extern "C" void kernel_launch(void* const* d_in, const int* in_sizes, int n_in,
                              void* d_out, int out_size, void* d_ws, size_t ws_size,
                              hipStream_t stream) {
    const float* x    = (const float*)d_in[0];
    const int*   ei   = (const int*)d_in[1];
    const int*   ae   = (const int*)d_in[2];
    const int*   army = (const int*)d_in[3];
    const float* W1   = (const float*)d_in[4];
    const float* b1   = (const float*)d_in[5];
    const float* W2   = (const float*)d_in[6];
    const float* b2   = (const float*)d_in[7];
    const float* Wp1  = (const float*)d_in[8];
    const float* bp1  = (const float*)d_in[9];
    const float* Wp2  = (const float*)d_in[10];
    const float* bp2  = (const float*)d_in[11];
    const float* We1  = (const float*)d_in[12];
    const float* be1  = (const float*)d_in[13];
    const float* We2  = (const float*)d_in[14];
    const float* be2  = (const float*)d_in[15];
    const float* Wa1  = (const float*)d_in[16];
    const float* ba1  = (const float*)d_in[17];
    const float* Wa2  = (const float*)d_in[18];
    const float* ba2  = (const float*)d_in[19];
    float* out = (float*)d_out;

    char* ws = (char*)d_ws;
    int*   cnt  = (int*)ws;                                   // 50000 ints
    float* dinv = (float*)(ws + 200000);                      // 50000 f
    float* A    = (float*)(ws + 400000);                      // 50000x64 f
    float* B    = (float*)(ws + 400000 + 12800000);           // 50000x64 f
    float* C    = (float*)(ws + 400000 + 25600000);           // 50000x64 f
    short* Wt   = (short*)(ws + 400000 + 38400000);           // 256x128 bf16

    // allow >64KB dynamic LDS for k_action (gfx950 LDS = 160KB/WG); ignore errors
    (void)hipFuncSetAttribute((const void*)k_action,
                              hipFuncAttributeMaxDynamicSharedMemorySize, 104448);

    hipMemsetAsync(cnt, 0, 200000, stream);
    k_count<<<6250, 256, 0, stream>>>(ei + NEDGE, cnt);
    k_dinv<<<196, 256, 0, stream>>>(cnt, dinv);

    // GCN layer 1
    k_gemm_nodes<128><<<12500, 256, 0, stream>>>(x, W1, A);
    hipMemsetAsync(B, 0, 12800000, stream);
    k_scatter<<<100000, 256, 0, stream>>>(A, B, ei, ei + NEDGE, dinv);
    k_finalize<<<3125, 256, 0, stream>>>(B, A, dinv, b1, C, 1);

    // GCN layer 2
    k_gemm_nodes<64><<<12500, 256, 0, stream>>>(C, W2, A);
    hipMemsetAsync(B, 0, 12800000, stream);
    k_scatter<<<100000, 256, 0, stream>>>(A, B, ei, ei + NEDGE, dinv);
    k_finalize<<<3125, 256, 0, stream>>>(B, A, dinv, b2, C, 0);

    // heads
    k_placement<<<12500, 256, 0, stream>>>(C, Wp1, bp1, Wp2, bp2, out);
    k_prep<<<128, 256, 0, stream>>>(We1, Wa1, Wa2, Wt);
    k_action<<<256, 512, 104448, stream>>>(C, ae, army, Wt,
                                           be1, We2, be2, ba1, ba2,
                                           out + NN, out + NN + NA);
}

// Round 2
// 1059.791 us; speedup vs baseline: 3.0754x; 3.0754x over previous
//
#include <hip/hip_runtime.h>

#define NN      50000
#define NEDGE   1600000
#define NA      1000000
#define FEATD   128
#define EMBD    64
#define MAXSEND 50
#define WSTR    136   // padded LDS row stride in shorts (128 + 8)

typedef __attribute__((ext_vector_type(4))) float  f32x4;
typedef __attribute__((ext_vector_type(8))) __bf16 bf16x8;
typedef __attribute__((ext_vector_type(8))) short  s16x8;

__device__ __forceinline__ short f2bf(float f) {
    union { float f; unsigned u; } v; v.f = f;
    unsigned r = (v.u + 0x7fffu + ((v.u >> 16) & 1u)) >> 16;  // RNE
    return (short)r;
}

// ---------------- degree count (in-degree over col) ----------------
__global__ void k_count(const int* __restrict__ col, int* __restrict__ cnt) {
    int e = blockIdx.x * 256 + threadIdx.x;
    if (e < NEDGE) atomicAdd(&cnt[col[e]], 1);
}

// ---------------- single-block exclusive scan -> off/cursor, plus dinv ----------------
__launch_bounds__(1024)
__global__ void k_scan(const int* __restrict__ cnt, int* __restrict__ off,
                       int* __restrict__ cursor, float* __restrict__ dinv) {
    __shared__ int ts[1024];
    const int CH = 49;                       // 1024*49 = 50176 >= NN
    int t = threadIdx.x;
    int base = t * CH;
    int s = 0;
    for (int i = 0; i < CH; i++) {
        int v = base + i;
        if (v < NN) s += cnt[v];
    }
    ts[t] = s;
    __syncthreads();
    for (int d = 1; d < 1024; d <<= 1) {
        int add = (t >= d) ? ts[t - d] : 0;
        __syncthreads();
        ts[t] += add;
        __syncthreads();
    }
    int run = (t == 0) ? 0 : ts[t - 1];
    for (int i = 0; i < CH; i++) {
        int v = base + i;
        if (v < NN) {
            off[v] = run;
            cursor[v] = run;
            int c = cnt[v];
            run += c;
            dinv[v] = rsqrtf((float)(c + 1));   // +1 self loop; always >= 1
        }
    }
    if (t == 0) off[NN] = NEDGE;
}

// ---------------- bucket edges by destination: esrc[pos] = row ----------------
__global__ void k_bucket(const int* __restrict__ row, const int* __restrict__ col,
                         int* __restrict__ cursor, int* __restrict__ esrc) {
    int e = blockIdx.x * 256 + threadIdx.x;
    if (e >= NEDGE) return;
    int pos = atomicAdd(&cursor[col[e]], 1);
    esrc[pos] = row[e];
}

// ---------------- node GEMM: Hs[v][j] = dinv[v] * sum_k X[v][k] W[k][j] ----------------
template <int K>
__global__ void k_gemm_nodes(const float* __restrict__ X, const float* __restrict__ W,
                             const float* __restrict__ dinv, float* __restrict__ Hs) {
    int wid  = (blockIdx.x * 256 + threadIdx.x) >> 6;  // one wave per node row
    int lane = threadIdx.x & 63;
    const float* xr = X + (long)wid * K;
    float x0 = xr[lane];
    float x1 = (K == 128) ? xr[lane + 64] : 0.f;
    float acc = 0.f;
#pragma unroll
    for (int k = 0; k < 64; k++) {
        float xv = __shfl(x0, k, 64);
        acc = fmaf(xv, W[k * EMBD + lane], acc);
    }
    if (K == 128) {
#pragma unroll
        for (int k = 0; k < 64; k++) {
            float xv = __shfl(x1, k, 64);
            acc = fmaf(xv, W[(k + 64) * EMBD + lane], acc);
        }
    }
    Hs[(long)wid * EMBD + lane] = acc * dinv[wid];
}

// ---------------- CSR gather: out[v] = relu?( dinv[v]*(sum_in Hs[r] + Hs[v]) + b ) ----------------
__global__ void k_gather(const float* __restrict__ Hs, const int* __restrict__ off,
                         const int* __restrict__ esrc, const float* __restrict__ dinv,
                         const float* __restrict__ b, float* __restrict__ out, int relu) {
    int wid  = (blockIdx.x * 256 + threadIdx.x) >> 6;  // one wave per node
    int lane = threadIdx.x & 63;
    int beg = off[wid], end = off[wid + 1];
    float acc = Hs[(long)wid * EMBD + lane];           // self loop (dinv[v] applied below)
    int i = beg;
    for (; i + 4 <= end; i += 4) {
        int r0 = esrc[i], r1 = esrc[i + 1], r2 = esrc[i + 2], r3 = esrc[i + 3];
        float v0 = Hs[(long)r0 * EMBD + lane];
        float v1 = Hs[(long)r1 * EMBD + lane];
        float v2 = Hs[(long)r2 * EMBD + lane];
        float v3 = Hs[(long)r3 * EMBD + lane];
        acc += v0 + v1 + v2 + v3;
    }
    for (; i < end; i++) acc += Hs[(long)esrc[i] * EMBD + lane];
    float o = acc * dinv[wid] + b[lane];
    out[(long)wid * EMBD + lane] = relu ? fmaxf(o, 0.f) : o;
}

// ---------------- placement head: one wave per node ----------------
__global__ void k_placement(const float* __restrict__ emb, const float* __restrict__ Wp1,
                            const float* __restrict__ bp1, const float* __restrict__ Wp2,
                            const float* __restrict__ bp2, float* __restrict__ out) {
    int wid  = (blockIdx.x * 256 + threadIdx.x) >> 6;
    int lane = threadIdx.x & 63;
    float e0 = emb[(long)wid * EMBD + lane];
    float acc = 0.f;
#pragma unroll
    for (int k = 0; k < 64; k++) {
        float ev = __shfl(e0, k, 64);
        acc = fmaf(ev, Wp1[k * 64 + lane], acc);
    }
    acc = fmaxf(acc + bp1[lane], 0.f) * Wp2[lane];
#pragma unroll
    for (int off = 32; off; off >>= 1) acc += __shfl_xor(acc, off, 64);
    if (lane == 0) out[wid] = acc + bp2[0];
}

// ---------------- weight prep: bf16 transposed [n][k], n: 0-63 We1, 64-191 Wa1, 192-255 Wa2(pad) --
__global__ void k_prep(const float* __restrict__ We1, const float* __restrict__ Wa1,
                       const float* __restrict__ Wa2, short* __restrict__ Wt) {
    int t = blockIdx.x * 256 + threadIdx.x;
    if (t >= 256 * 128) return;
    int n = t >> 7, k = t & 127;
    float v;
    if (n < 64)       v = We1[k * 64 + n];
    else if (n < 192) v = Wa1[k * 128 + (n - 64)];
    else { int n2 = n - 192; v = (n2 < MAXSEND) ? Wa2[k * MAXSEND + n2] : 0.f; }
    Wt[t] = f2bf(v);
}

// ---------------- action-edge MLP: bf16 MFMA, one 16-action m-tile per wave ----------------
__launch_bounds__(512, 1)
__global__ void k_action(const float* __restrict__ emb, const int* __restrict__ ae,
                         const int* __restrict__ army, const short* __restrict__ Wt,
                         const float* __restrict__ be1, const float* __restrict__ We2,
                         const float* __restrict__ be2, const float* __restrict__ ba1,
                         const float* __restrict__ ba2,
                         float* __restrict__ out_edge, float* __restrict__ out_army) {
    extern __shared__ short lds[];
    int tid = threadIdx.x;
    // stage all weights into padded LDS (rows 0..255, stride WSTR shorts)
    for (int i = tid; i < 4096; i += 512) {
        int rw = i >> 4, c8 = (i & 15) * 8;
        *(uint4*)(lds + rw * WSTR + c8) = *(const uint4*)(Wt + rw * 128 + c8);
    }
    __syncthreads();

    int w = tid >> 6, lane = tid & 63;
    int m = lane & 15, q = lane >> 4;   // MFMA lane decomposition
    short* a1s = lds + 256 * WSTR + w * 16 * WSTR;  // per-wave 16x136 bf16 scratch

    float be1v[4], w2v[4], ba1v[8], ba2v[4];
#pragma unroll
    for (int t = 0; t < 4; t++) { be1v[t] = be1[t * 16 + m]; w2v[t] = We2[t * 16 + m]; }
#pragma unroll
    for (int t = 0; t < 8; t++) ba1v[t] = ba1[t * 16 + m];
#pragma unroll
    for (int nt = 0; nt < 4; nt++) { int n = nt * 16 + m; ba2v[nt] = (n < MAXSEND) ? ba2[n] : 0.f; }
    float be2v = be2[0];
    const f32x4 zero = {0.f, 0.f, 0.f, 0.f};

    int gw = blockIdx.x * 8 + w;
    int nwaves = gridDim.x * 8;
    for (int tile = gw; tile < NA / 16; tile += nwaves) {
        int a0 = tile * 16;
        // A-fragments: lane holds EE[a0+m][kk*32 + q*8 + j], EE = concat(emb[src], emb[tgt])
        int2 st = ((const int2*)ae)[a0 + m];
        s16x8 af[4];
#pragma unroll
        for (int kk = 0; kk < 4; kk++) {
            const float* base = (kk < 2) ? (emb + (long)st.x * 64 + kk * 32 + q * 8)
                                         : (emb + (long)st.y * 64 + (kk - 2) * 32 + q * 8);
            float4 u0 = *(const float4*)(base);
            float4 u1 = *(const float4*)(base + 4);
            s16x8 f;
            f[0] = f2bf(u0.x); f[1] = f2bf(u0.y); f[2] = f2bf(u0.z); f[3] = f2bf(u0.w);
            f[4] = f2bf(u1.x); f[5] = f2bf(u1.y); f[6] = f2bf(u1.z); f[7] = f2bf(u1.w);
            af[kk] = f;
        }
        // stage 1: n-tiles 0..3 -> e1 (We1 rows 0..63), 4..11 -> a1 (Wa1 rows 64..191)
        f32x4 acc[12];
#pragma unroll
        for (int t = 0; t < 12; t++) acc[t] = zero;
#pragma unroll
        for (int t = 0; t < 12; t++) {
#pragma unroll
            for (int kk = 0; kk < 4; kk++) {
                s16x8 bfrag = *(const s16x8*)(lds + (t * 16 + m) * WSTR + kk * 32 + q * 8);
                acc[t] = __builtin_amdgcn_mfma_f32_16x16x32_bf16(
                    __builtin_bit_cast(bf16x8, af[kk]),
                    __builtin_bit_cast(bf16x8, bfrag), acc[t], 0, 0, 0);
            }
        }
        // e1 epilogue -> edge-logit partials (C layout: row a=q*4+r, col j=t*16+m)
        float elp[4] = {0.f, 0.f, 0.f, 0.f};
#pragma unroll
        for (int t = 0; t < 4; t++) {
#pragma unroll
            for (int r = 0; r < 4; r++) {
                float v = fmaxf(acc[t][r] + be1v[t], 0.f);
                elp[r] = fmaf(v, w2v[t], elp[r]);
            }
        }
        // a1 epilogue -> bf16 into per-wave LDS scratch (row-major [16][WSTR])
#pragma unroll
        for (int t = 4; t < 12; t++) {
#pragma unroll
            for (int r = 0; r < 4; r++) {
                float v = fmaxf(acc[t][r] + ba1v[t - 4], 0.f);
                a1s[(q * 4 + r) * WSTR + (t - 4) * 16 + m] = f2bf(v);
            }
        }
        // reduce edge logits over the 16 j-lanes in each quad
#pragma unroll
        for (int r = 0; r < 4; r++) {
            float s = elp[r];
            s += __shfl_xor(s, 1, 64);
            s += __shfl_xor(s, 2, 64);
            s += __shfl_xor(s, 4, 64);
            s += __shfl_xor(s, 8, 64);
            elp[r] = s;
        }
        if (m == 0) {
#pragma unroll
            for (int r = 0; r < 4; r++) {
                int aa = a0 + q * 4 + r;
                int2 st2 = ((const int2*)ae)[aa];
                int sa = army[st2.x], ta = army[st2.y];
                float adj = ((sa <= 2) || (ta >= 3 * sa)) ? 1.f : 0.f;
                if (st2.x == st2.y) adj += 100.f;
                out_edge[aa] = elp[r] + be2v - adj;
            }
        }
        // src army counts for masking (rows a=q*4+r)
        int sa_loc[4];
#pragma unroll
        for (int r = 0; r < 4; r++) {
            int aa = a0 + q * 4 + r;
            sa_loc[r] = army[((const int2*)ae)[aa].x];
        }
        __asm__ volatile("s_waitcnt lgkmcnt(0)" ::: "memory");  // a1s writes -> reads
        // stage 2: army = relu(a1) @ Wa2 (rows 192..255 in LDS, cols padded to 64)
        s16x8 a2[4];
#pragma unroll
        for (int kk = 0; kk < 4; kk++)
            a2[kk] = *(const s16x8*)(a1s + m * WSTR + kk * 32 + q * 8);
#pragma unroll
        for (int nt = 0; nt < 4; nt++) {
            f32x4 c2 = zero;
#pragma unroll
            for (int kk = 0; kk < 4; kk++) {
                s16x8 bfrag = *(const s16x8*)(lds + (192 + nt * 16 + m) * WSTR + kk * 32 + q * 8);
                c2 = __builtin_amdgcn_mfma_f32_16x16x32_bf16(
                    __builtin_bit_cast(bf16x8, a2[kk]),
                    __builtin_bit_cast(bf16x8, bfrag), c2, 0, 0, 0);
            }
            int n = nt * 16 + m;
            if (n < MAXSEND) {
#pragma unroll
                for (int r = 0; r < 4; r++) {
                    int aa = a0 + q * 4 + r;
                    float v = c2[r] + ba2v[nt];
                    out_army[(long)aa * MAXSEND + n] = (n < sa_loc[r]) ? v : -1e9f;
                }
            }
        }
    }
}

extern "C" void kernel_launch(void* const* d_in, const int* in_sizes, int n_in,
                              void* d_out, int out_size, void* d_ws, size_t ws_size,
                              hipStream_t stream) {
    const float* x    = (const float*)d_in[0];
    const int*   ei   = (const int*)d_in[1];
    const int*   ae   = (const int*)d_in[2];
    const int*   army = (const int*)d_in[3];
    const float* W1   = (const float*)d_in[4];
    const float* b1   = (const float*)d_in[5];
    const float* W2   = (const float*)d_in[6];
    const float* b2   = (const float*)d_in[7];
    const float* Wp1  = (const float*)d_in[8];
    const float* bp1  = (const float*)d_in[9];
    const float* Wp2  = (const float*)d_in[10];
    const float* bp2  = (const float*)d_in[11];
    const float* We1  = (const float*)d_in[12];
    const float* be1  = (const float*)d_in[13];
    const float* We2  = (const float*)d_in[14];
    const float* be2  = (const float*)d_in[15];
    const float* Wa1  = (const float*)d_in[16];
    const float* ba1  = (const float*)d_in[17];
    const float* Wa2  = (const float*)d_in[18];
    const float* ba2  = (const float*)d_in[19];
    float* out = (float*)d_out;

    char* ws = (char*)d_ws;
    int*   cnt    = (int*)ws;                                 // 50000 ints
    float* dinv   = (float*)(ws + 200000);                    // 50000 f
    int*   off    = (int*)(ws + 400000);                      // 50001 ints
    int*   cursor = (int*)(ws + 600008);                      // 50000 ints
    int*   esrc   = (int*)(ws + 800008);                      // 1.6M ints
    float* A      = (float*)(ws + 7200008);                   // 50000x64 f (Hs)
    float* C      = (float*)(ws + 7200008 + 12800000);        // 50000x64 f (h / emb)
    short* Wt     = (short*)(ws + 7200008 + 25600000);        // 256x128 bf16

    // allow >64KB dynamic LDS for k_action (gfx950 LDS = 160KB/WG); ignore errors
    (void)hipFuncSetAttribute((const void*)k_action,
                              hipFuncAttributeMaxDynamicSharedMemorySize, 104448);

    // ---- CSR build (once per launch) ----
    hipMemsetAsync(cnt, 0, 200000, stream);
    k_count<<<6250, 256, 0, stream>>>(ei + NEDGE, cnt);
    k_scan<<<1, 1024, 0, stream>>>(cnt, off, cursor, dinv);
    k_bucket<<<6250, 256, 0, stream>>>(ei, ei + NEDGE, cursor, esrc);

    // ---- GCN layer 1: h = relu(gather(x@W1 * dinv) * dinv + b1) ----
    k_gemm_nodes<128><<<12500, 256, 0, stream>>>(x, W1, dinv, A);
    k_gather<<<12500, 256, 0, stream>>>(A, off, esrc, dinv, b1, C, 1);

    // ---- GCN layer 2: emb = gather(h@W2 * dinv) * dinv + b2 ----
    k_gemm_nodes<64><<<12500, 256, 0, stream>>>(C, W2, dinv, A);
    k_gather<<<12500, 256, 0, stream>>>(A, off, esrc, dinv, b2, C, 0);

    // ---- heads ----
    k_placement<<<12500, 256, 0, stream>>>(C, Wp1, bp1, Wp2, bp2, out);
    k_prep<<<128, 256, 0, stream>>>(We1, Wa1, Wa2, Wt);
    k_action<<<256, 512, 104448, stream>>>(C, ae, army, Wt,
                                           be1, We2, be2, ba1, ba2,
                                           out + NN, out + NN + NA);
}

// Round 3
// 914.523 us; speedup vs baseline: 3.5639x; 1.1588x over previous
//
#include <hip/hip_runtime.h>

#define NN      50000
#define NEDGE   1600000
#define NA      1000000
#define FEATD   128
#define EMBD    64
#define MAXSEND 50
#define RSTR    136   // padded LDS row stride in BYTES (128 fp8 + 8 pad)

typedef __attribute__((ext_vector_type(4))) float f32x4;

__device__ __forceinline__ unsigned char f2fp8(float f) {
    int p = __builtin_amdgcn_cvt_pk_fp8_f32(f, f, 0, false);
    return (unsigned char)(p & 0xff);
}

// ---------------- degree count (in-degree over col) ----------------
__global__ void k_count(const int* __restrict__ col, int* __restrict__ cnt) {
    int e = blockIdx.x * 256 + threadIdx.x;
    if (e < NEDGE) atomicAdd(&cnt[col[e]], 1);
}

// ---------------- single-block exclusive scan -> off/cursor, plus dinv ----------------
__launch_bounds__(1024)
__global__ void k_scan(const int* __restrict__ cnt, int* __restrict__ off,
                       int* __restrict__ cursor, float* __restrict__ dinv) {
    __shared__ int ts[1024];
    const int CH = 49;                       // 1024*49 = 50176 >= NN
    int t = threadIdx.x;
    int base = t * CH;
    int s = 0;
    for (int i = 0; i < CH; i++) {
        int v = base + i;
        if (v < NN) s += cnt[v];
    }
    ts[t] = s;
    __syncthreads();
    for (int d = 1; d < 1024; d <<= 1) {
        int add = (t >= d) ? ts[t - d] : 0;
        __syncthreads();
        ts[t] += add;
        __syncthreads();
    }
    int run = (t == 0) ? 0 : ts[t - 1];
    for (int i = 0; i < CH; i++) {
        int v = base + i;
        if (v < NN) {
            off[v] = run;
            cursor[v] = run;
            int c = cnt[v];
            run += c;
            dinv[v] = rsqrtf((float)(c + 1));   // +1 self loop; always >= 1
        }
    }
    if (t == 0) off[NN] = NEDGE;
}

// ---------------- bucket edges by destination: esrc[pos] = row ----------------
__global__ void k_bucket(const int* __restrict__ row, const int* __restrict__ col,
                         int* __restrict__ cursor, int* __restrict__ esrc) {
    int e = blockIdx.x * 256 + threadIdx.x;
    if (e >= NEDGE) return;
    int pos = atomicAdd(&cursor[col[e]], 1);
    esrc[pos] = row[e];
}

// ---------------- node GEMM: Hs[v][j] = dinv[v] * sum_k X[v][k] W[k][j] ----------------
__global__ void k_gemm_nodes(const float* __restrict__ X, const float* __restrict__ W,
                             const float* __restrict__ dinv, float* __restrict__ Hs) {
    int wid  = (blockIdx.x * 256 + threadIdx.x) >> 6;  // one wave per node row
    int lane = threadIdx.x & 63;
    const float* xr = X + (long)wid * FEATD;
    float x0 = xr[lane];
    float x1 = xr[lane + 64];
    float acc = 0.f;
#pragma unroll
    for (int k = 0; k < 64; k++) {
        float xv = __shfl(x0, k, 64);
        acc = fmaf(xv, W[k * EMBD + lane], acc);
    }
#pragma unroll
    for (int k = 0; k < 64; k++) {
        float xv = __shfl(x1, k, 64);
        acc = fmaf(xv, W[(k + 64) * EMBD + lane], acc);
    }
    Hs[(long)wid * EMBD + lane] = acc * dinv[wid];
}

// ---- gather layer 1 fused with layer-2 node GEMM:
//      h = relu(dinv*(gather Hs1)+b1); Hs2 = dinv * (h @ W2) ----
__global__ void k_gather1(const float* __restrict__ Hs, const int* __restrict__ off,
                          const int* __restrict__ esrc, const float* __restrict__ dinv,
                          const float* __restrict__ b1, const float* __restrict__ W2,
                          float* __restrict__ Hs2) {
    int wid  = (blockIdx.x * 256 + threadIdx.x) >> 6;  // one wave per node
    int lane = threadIdx.x & 63;
    int beg = off[wid], end = off[wid + 1];
    float acc = Hs[(long)wid * EMBD + lane];           // self loop
    int i = beg;
    for (; i + 4 <= end; i += 4) {
        int r0 = esrc[i], r1 = esrc[i + 1], r2 = esrc[i + 2], r3 = esrc[i + 3];
        acc += Hs[(long)r0 * EMBD + lane] + Hs[(long)r1 * EMBD + lane]
             + Hs[(long)r2 * EMBD + lane] + Hs[(long)r3 * EMBD + lane];
    }
    for (; i < end; i++) acc += Hs[(long)esrc[i] * EMBD + lane];
    float d = dinv[wid];
    float h = fmaxf(acc * d + b1[lane], 0.f);
    float a2 = 0.f;
#pragma unroll
    for (int k = 0; k < 64; k++) {
        float hv = __shfl(h, k, 64);
        a2 = fmaf(hv, W2[k * EMBD + lane], a2);
    }
    Hs2[(long)wid * EMBD + lane] = a2 * d;
}

// ---- gather layer 2 fused with placement head + fp8 emb pack ----
__global__ void k_gather2(const float* __restrict__ Hs, const int* __restrict__ off,
                          const int* __restrict__ esrc, const float* __restrict__ dinv,
                          const float* __restrict__ b2,
                          const float* __restrict__ Wp1, const float* __restrict__ bp1,
                          const float* __restrict__ Wp2, const float* __restrict__ bp2,
                          float* __restrict__ out_place, unsigned char* __restrict__ emb8) {
    int wid  = (blockIdx.x * 256 + threadIdx.x) >> 6;  // one wave per node
    int lane = threadIdx.x & 63;
    int beg = off[wid], end = off[wid + 1];
    float acc = Hs[(long)wid * EMBD + lane];
    int i = beg;
    for (; i + 4 <= end; i += 4) {
        int r0 = esrc[i], r1 = esrc[i + 1], r2 = esrc[i + 2], r3 = esrc[i + 3];
        acc += Hs[(long)r0 * EMBD + lane] + Hs[(long)r1 * EMBD + lane]
             + Hs[(long)r2 * EMBD + lane] + Hs[(long)r3 * EMBD + lane];
    }
    for (; i < end; i++) acc += Hs[(long)esrc[i] * EMBD + lane];
    float o = acc * dinv[wid] + b2[lane];              // emb value (fp32)
    // placement head
    float p = 0.f;
#pragma unroll
    for (int k = 0; k < 64; k++) {
        float ev = __shfl(o, k, 64);
        p = fmaf(ev, Wp1[k * 64 + lane], p);
    }
    p = fmaxf(p + bp1[lane], 0.f) * Wp2[lane];
#pragma unroll
    for (int d = 32; d; d >>= 1) p += __shfl_xor(p, d, 64);
    if (lane == 0) out_place[wid] = p + bp2[0];
    // fp8 pack of emb row (4 lanes -> 1 dword)
    float o1 = __shfl_down(o, 1, 64);
    float o2 = __shfl_down(o, 2, 64);
    float o3 = __shfl_down(o, 3, 64);
    int pk = __builtin_amdgcn_cvt_pk_fp8_f32(o, o1, 0, false);
    pk = __builtin_amdgcn_cvt_pk_fp8_f32(o2, o3, pk, true);
    if ((lane & 3) == 0)
        *(int*)(emb8 + (long)wid * EMBD + lane) = pk;
}

// ---- weight prep: fp8 transposed [n][k]; n: 0-63 We1, 64-191 Wa1, 192-255 Wa2(pad) ----
__global__ void k_prep(const float* __restrict__ We1, const float* __restrict__ Wa1,
                       const float* __restrict__ Wa2, unsigned char* __restrict__ Wt8) {
    int t = blockIdx.x * 256 + threadIdx.x;
    if (t >= 256 * 128) return;
    int n = t >> 7, k = t & 127;
    float v;
    if (n < 64)       v = We1[k * 64 + n];
    else if (n < 192) v = Wa1[k * 128 + (n - 64)];
    else { int n2 = n - 192; v = (n2 < MAXSEND) ? Wa2[k * MAXSEND + n2] : 0.f; }
    Wt8[t] = f2fp8(v);
}

// ---------------- action-edge MLP: fp8 MFMA, one 16-action m-tile per wave ----------------
__launch_bounds__(512, 4)
__global__ void k_action(const unsigned char* __restrict__ emb8, const int* __restrict__ ae,
                         const int* __restrict__ army, const unsigned char* __restrict__ Wt8,
                         const float* __restrict__ be1, const float* __restrict__ We2,
                         const float* __restrict__ be2, const float* __restrict__ ba1,
                         const float* __restrict__ ba2,
                         float* __restrict__ out_edge, float* __restrict__ out_army) {
    extern __shared__ char lds8[];
    int tid = threadIdx.x;
    // stage fp8 weights into padded LDS (256 rows x RSTR bytes)
    for (int i = tid; i < 2048; i += 512) {
        int rw = i >> 3, c16 = (i & 7) * 16;
        *(uint4*)(lds8 + rw * RSTR + c16) = *(const uint4*)(Wt8 + rw * 128 + c16);
    }
    __syncthreads();

    int w = tid >> 6, lane = tid & 63;
    int m = lane & 15, q = lane >> 4;                  // MFMA lane decomposition
    char* a1s = lds8 + 256 * RSTR + w * 16 * RSTR;     // per-wave 16xRSTR fp8 scratch

    float be1v[4], w2v[4], ba1v[8], ba2v[4];
#pragma unroll
    for (int t = 0; t < 4; t++) { be1v[t] = be1[t * 16 + m]; w2v[t] = We2[t * 16 + m]; }
#pragma unroll
    for (int t = 0; t < 8; t++) ba1v[t] = ba1[t * 16 + m];
#pragma unroll
    for (int nt = 0; nt < 4; nt++) { int n = nt * 16 + m; ba2v[nt] = (n < MAXSEND) ? ba2[n] : 0.f; }
    float be2v = be2[0];
    const f32x4 zero = {0.f, 0.f, 0.f, 0.f};

    int gw = blockIdx.x * 8 + w;
    int nwaves = gridDim.x * 8;
    for (int tile = gw; tile < NA / 16; tile += nwaves) {
        int a0 = tile * 16;
        // per-action (lane m holds action a0+m): src/tgt, armies, mask adjustment
        int2 st = ((const int2*)ae)[a0 + m];
        int army_s = army[st.x];
        int army_t = army[st.y];
        float adj_m = ((army_s <= 2) || (army_t >= 3 * army_s)) ? 1.f : 0.f;
        if (st.x == st.y) adj_m += 100.f;
        // A-fragments: lane holds EE[a0+m][kk*32 + q*8 ..+7] as fp8 bytes
        long af[4];
        af[0] = *(const long*)(emb8 + (long)st.x * EMBD + q * 8);
        af[1] = *(const long*)(emb8 + (long)st.x * EMBD + 32 + q * 8);
        af[2] = *(const long*)(emb8 + (long)st.y * EMBD + q * 8);
        af[3] = *(const long*)(emb8 + (long)st.y * EMBD + 32 + q * 8);
        // broadcast per-row (a = q*4+r) army/adj to all lanes
        float adjr[4]; int sar[4];
#pragma unroll
        for (int r = 0; r < 4; r++) {
            int rowlane = q * 4 + r;
            adjr[r] = __shfl(adj_m, rowlane, 64);
            sar[r]  = __shfl(army_s, rowlane, 64);
        }
        // stage 1: n-tiles 0..3 -> e1 (We1 rows), 4..11 -> a1 (Wa1 rows)
        f32x4 acc[12];
#pragma unroll
        for (int t = 0; t < 12; t++) acc[t] = zero;
#pragma unroll
        for (int t = 0; t < 12; t++) {
#pragma unroll
            for (int kk = 0; kk < 4; kk++) {
                long bfrag = *(const long*)(lds8 + (t * 16 + m) * RSTR + kk * 32 + q * 8);
                acc[t] = __builtin_amdgcn_mfma_f32_16x16x32_fp8_fp8(af[kk], bfrag, acc[t], 0, 0, 0);
            }
        }
        // e1 epilogue -> edge-logit partials (C layout: row a=q*4+r, col j=t*16+m)
        float elp[4] = {0.f, 0.f, 0.f, 0.f};
#pragma unroll
        for (int t = 0; t < 4; t++) {
#pragma unroll
            for (int r = 0; r < 4; r++) {
                float v = fmaxf(acc[t][r] + be1v[t], 0.f);
                elp[r] = fmaf(v, w2v[t], elp[r]);
            }
        }
        // a1 epilogue -> fp8 into per-wave LDS scratch
#pragma unroll
        for (int t = 4; t < 12; t++) {
#pragma unroll
            for (int r = 0; r < 4; r++) {
                float v = fmaxf(acc[t][r] + ba1v[t - 4], 0.f);
                a1s[(q * 4 + r) * RSTR + (t - 4) * 16 + m] = (char)f2fp8(v);
            }
        }
        // reduce edge logits over the 16 j-lanes in each quad
#pragma unroll
        for (int r = 0; r < 4; r++) {
            float s = elp[r];
            s += __shfl_xor(s, 1, 64);
            s += __shfl_xor(s, 2, 64);
            s += __shfl_xor(s, 4, 64);
            s += __shfl_xor(s, 8, 64);
            elp[r] = s;
        }
        if (m == 0) {
#pragma unroll
            for (int r = 0; r < 4; r++)
                out_edge[a0 + q * 4 + r] = elp[r] + be2v - adjr[r];
        }
        __asm__ volatile("s_waitcnt lgkmcnt(0)" ::: "memory");  // a1s writes -> reads
        // stage 2: army = relu(a1) @ Wa2 (rows 192..255 in LDS, cols padded to 64)
        long a2f[4];
#pragma unroll
        for (int kk = 0; kk < 4; kk++)
            a2f[kk] = *(const long*)(a1s + m * RSTR + kk * 32 + q * 8);
#pragma unroll
        for (int nt = 0; nt < 4; nt++) {
            f32x4 c2 = zero;
#pragma unroll
            for (int kk = 0; kk < 4; kk++) {
                long bfrag = *(const long*)(lds8 + (192 + nt * 16 + m) * RSTR + kk * 32 + q * 8);
                c2 = __builtin_amdgcn_mfma_f32_16x16x32_fp8_fp8(a2f[kk], bfrag, c2, 0, 0, 0);
            }
            int n = nt * 16 + m;
            if (n < MAXSEND) {
#pragma unroll
                for (int r = 0; r < 4; r++) {
                    int aa = a0 + q * 4 + r;
                    float v = c2[r] + ba2v[nt];
                    out_army[(long)aa * MAXSEND + n] = (n < sar[r]) ? v : -1e9f;
                }
            }
        }
    }
}

extern "C" void kernel_launch(void* const* d_in, const int* in_sizes, int n_in,
                              void* d_out, int out_size, void* d_ws, size_t ws_size,
                              hipStream_t stream) {
    const float* x    = (const float*)d_in[0];
    const int*   ei   = (const int*)d_in[1];
    const int*   ae   = (const int*)d_in[2];
    const int*   army = (const int*)d_in[3];
    const float* W1   = (const float*)d_in[4];
    const float* b1   = (const float*)d_in[5];
    const float* W2   = (const float*)d_in[6];
    const float* b2   = (const float*)d_in[7];
    const float* Wp1  = (const float*)d_in[8];
    const float* bp1  = (const float*)d_in[9];
    const float* Wp2  = (const float*)d_in[10];
    const float* bp2  = (const float*)d_in[11];
    const float* We1  = (const float*)d_in[12];
    const float* be1  = (const float*)d_in[13];
    const float* We2  = (const float*)d_in[14];
    const float* be2  = (const float*)d_in[15];
    const float* Wa1  = (const float*)d_in[16];
    const float* ba1  = (const float*)d_in[17];
    const float* Wa2  = (const float*)d_in[18];
    const float* ba2  = (const float*)d_in[19];
    float* out = (float*)d_out;

    char* ws = (char*)d_ws;
    int*           cnt    = (int*)ws;                         // 50000 ints
    float*         dinv   = (float*)(ws + 200000);            // 50000 f
    int*           off    = (int*)(ws + 400000);              // 50001 ints
    int*           cursor = (int*)(ws + 600064);              // 50000 ints
    int*           esrc   = (int*)(ws + 800064);              // 1.6M ints
    float*         A      = (float*)(ws + 7200064);           // 50000x64 f (Hs1)
    float*         B      = (float*)(ws + 20000064);          // 50000x64 f (Hs2)
    unsigned char* emb8   = (unsigned char*)(ws + 32800064);  // 50000x64 fp8
    unsigned char* Wt8    = (unsigned char*)(ws + 36000064);  // 256x128 fp8

    // ---- CSR build (once per launch) ----
    hipMemsetAsync(cnt, 0, 200000, stream);
    k_count<<<6250, 256, 0, stream>>>(ei + NEDGE, cnt);
    k_scan<<<1, 1024, 0, stream>>>(cnt, off, cursor, dinv);
    k_bucket<<<6250, 256, 0, stream>>>(ei, ei + NEDGE, cursor, esrc);

    // ---- GCN layer 1 GEMM, then fused gather1+GEMM2, fused gather2+placement ----
    k_gemm_nodes<<<12500, 256, 0, stream>>>(x, W1, dinv, A);
    k_gather1<<<12500, 256, 0, stream>>>(A, off, esrc, dinv, b1, W2, B);
    k_gather2<<<12500, 256, 0, stream>>>(B, off, esrc, dinv, b2, Wp1, bp1, Wp2, bp2,
                                         out, emb8);

    // ---- action head (fp8 MFMA) ----
    k_prep<<<128, 256, 0, stream>>>(We1, Wa1, Wa2, Wt8);
    k_action<<<768, 512, 256 * RSTR + 8 * 16 * RSTR, stream>>>(
        emb8, ae, army, Wt8, be1, We2, be2, ba1, ba2, out + NN, out + NN + NA);
}

// Round 4
// 773.046 us; speedup vs baseline: 4.2161x; 1.1830x over previous
//
#include <hip/hip_runtime.h>

#define NN      50000
#define NEDGE   1600000
#define NA      1000000
#define FEATD   128
#define EMBD    64
#define MAXSEND 50
#define RSTR    136   // padded LDS row stride in BYTES (128 fp8 + 8 pad)
#define NBLK    196   // scan blocks: 196*256 = 50176 >= NN

typedef __attribute__((ext_vector_type(4))) float f32x4;

__device__ __forceinline__ unsigned char f2fp8(float f) {
    int p = __builtin_amdgcn_cvt_pk_fp8_f32(f, f, 0, false);
    return (unsigned char)(p & 0xff);
}

__device__ __forceinline__ int wave_incl_scan(int v, int lane) {
#pragma unroll
    for (int d = 1; d < 64; d <<= 1) {
        int u = __shfl_up(v, d, 64);
        v += (lane >= d) ? u : 0;
    }
    return v;
}

// ---------------- degree count (in-degree over col) ----------------
__global__ void k_count(const int* __restrict__ col, int* __restrict__ cnt) {
    int e = blockIdx.x * 256 + threadIdx.x;
    if (e < NEDGE) atomicAdd(&cnt[col[e]], 1);
}

// ---------------- parallel scan stage 1: per-block sums ----------------
__global__ void k_scan1(const int* __restrict__ cnt, int* __restrict__ bsum) {
    int t = blockIdx.x * 256 + threadIdx.x;
    int v = (t < NN) ? cnt[t] : 0;
    int lane = threadIdx.x & 63, w = threadIdx.x >> 6;
    __shared__ int ws[4];
#pragma unroll
    for (int d = 32; d; d >>= 1) v += __shfl_xor(v, d, 64);
    if (lane == 0) ws[w] = v;
    __syncthreads();
    if (threadIdx.x == 0) bsum[blockIdx.x] = ws[0] + ws[1] + ws[2] + ws[3];
}

// ---------------- parallel scan stage 2: exclusive scan of block sums ----------------
__global__ void k_scan2(const int* __restrict__ bsum, int* __restrict__ boff) {
    int t = threadIdx.x;
    int v = (t < NBLK) ? bsum[t] : 0;
    int lane = t & 63, w = t >> 6;
    int inc = wave_incl_scan(v, lane);
    __shared__ int ws[4];
    if (lane == 63) ws[w] = inc;
    __syncthreads();
    int add = 0;
    for (int i = 0; i < w; i++) add += ws[i];
    if (t < NBLK) boff[t] = inc - v + add;
}

// ---------------- parallel scan stage 3: intra-block scan + offsets/dinv ----------------
__global__ void k_scan3(const int* __restrict__ cnt, const int* __restrict__ boff,
                        int* __restrict__ off, int* __restrict__ cursor,
                        float* __restrict__ dinv) {
    int t = blockIdx.x * 256 + threadIdx.x;
    int c = (t < NN) ? cnt[t] : 0;
    int lane = threadIdx.x & 63, w = threadIdx.x >> 6;
    int inc = wave_incl_scan(c, lane);
    __shared__ int ws[4];
    if (lane == 63) ws[w] = inc;
    __syncthreads();
    int add = boff[blockIdx.x];
    for (int i = 0; i < w; i++) add += ws[i];
    int exc = inc - c + add;
    if (t < NN) {
        off[t] = exc;
        cursor[t] = exc;
        dinv[t] = rsqrtf((float)(c + 1));   // +1 self loop; always >= 1
    }
    if (t == 0) off[NN] = NEDGE;
}

// ---------------- bucket edges by destination: esrc[pos] = row ----------------
__global__ void k_bucket(const int* __restrict__ row, const int* __restrict__ col,
                         int* __restrict__ cursor, int* __restrict__ esrc) {
    int e = blockIdx.x * 256 + threadIdx.x;
    if (e >= NEDGE) return;
    int pos = atomicAdd(&cursor[col[e]], 1);
    esrc[pos] = row[e];
}

// ---------------- node GEMM: Hs[v][j] = dinv[v] * sum_k X[v][k] W[k][j] ----------------
__global__ void k_gemm_nodes(const float* __restrict__ X, const float* __restrict__ W,
                             const float* __restrict__ dinv, float* __restrict__ Hs) {
    int wid  = (blockIdx.x * 256 + threadIdx.x) >> 6;  // one wave per node row
    int lane = threadIdx.x & 63;
    const float* xr = X + (long)wid * FEATD;
    float x0 = xr[lane];
    float x1 = xr[lane + 64];
    float acc = 0.f;
#pragma unroll
    for (int k = 0; k < 64; k++) {
        float xv = __shfl(x0, k, 64);
        acc = fmaf(xv, W[k * EMBD + lane], acc);
    }
#pragma unroll
    for (int k = 0; k < 64; k++) {
        float xv = __shfl(x1, k, 64);
        acc = fmaf(xv, W[(k + 64) * EMBD + lane], acc);
    }
    Hs[(long)wid * EMBD + lane] = acc * dinv[wid];
}

// ---- gather layer 1 fused with layer-2 node GEMM:
//      h = relu(dinv*(gather Hs1)+b1); Hs2 = dinv * (h @ W2) ----
__global__ void k_gather1(const float* __restrict__ Hs, const int* __restrict__ off,
                          const int* __restrict__ esrc, const float* __restrict__ dinv,
                          const float* __restrict__ b1, const float* __restrict__ W2,
                          float* __restrict__ Hs2) {
    int wid  = (blockIdx.x * 256 + threadIdx.x) >> 6;  // one wave per node
    int lane = threadIdx.x & 63;
    int beg = off[wid], end = off[wid + 1];
    float acc = Hs[(long)wid * EMBD + lane];           // self loop
    int i = beg;
    for (; i + 4 <= end; i += 4) {
        int r0 = esrc[i], r1 = esrc[i + 1], r2 = esrc[i + 2], r3 = esrc[i + 3];
        acc += Hs[(long)r0 * EMBD + lane] + Hs[(long)r1 * EMBD + lane]
             + Hs[(long)r2 * EMBD + lane] + Hs[(long)r3 * EMBD + lane];
    }
    for (; i < end; i++) acc += Hs[(long)esrc[i] * EMBD + lane];
    float d = dinv[wid];
    float h = fmaxf(acc * d + b1[lane], 0.f);
    float a2 = 0.f;
#pragma unroll
    for (int k = 0; k < 64; k++) {
        float hv = __shfl(h, k, 64);
        a2 = fmaf(hv, W2[k * EMBD + lane], a2);
    }
    Hs2[(long)wid * EMBD + lane] = a2 * d;
}

// ---- gather layer 2 fused with placement head + fp8 emb pack ----
__global__ void k_gather2(const float* __restrict__ Hs, const int* __restrict__ off,
                          const int* __restrict__ esrc, const float* __restrict__ dinv,
                          const float* __restrict__ b2,
                          const float* __restrict__ Wp1, const float* __restrict__ bp1,
                          const float* __restrict__ Wp2, const float* __restrict__ bp2,
                          float* __restrict__ out_place, unsigned char* __restrict__ emb8) {
    int wid  = (blockIdx.x * 256 + threadIdx.x) >> 6;  // one wave per node
    int lane = threadIdx.x & 63;
    int beg = off[wid], end = off[wid + 1];
    float acc = Hs[(long)wid * EMBD + lane];
    int i = beg;
    for (; i + 4 <= end; i += 4) {
        int r0 = esrc[i], r1 = esrc[i + 1], r2 = esrc[i + 2], r3 = esrc[i + 3];
        acc += Hs[(long)r0 * EMBD + lane] + Hs[(long)r1 * EMBD + lane]
             + Hs[(long)r2 * EMBD + lane] + Hs[(long)r3 * EMBD + lane];
    }
    for (; i < end; i++) acc += Hs[(long)esrc[i] * EMBD + lane];
    float o = acc * dinv[wid] + b2[lane];              // emb value (fp32)
    // placement head
    float p = 0.f;
#pragma unroll
    for (int k = 0; k < 64; k++) {
        float ev = __shfl(o, k, 64);
        p = fmaf(ev, Wp1[k * 64 + lane], p);
    }
    p = fmaxf(p + bp1[lane], 0.f) * Wp2[lane];
#pragma unroll
    for (int d = 32; d; d >>= 1) p += __shfl_xor(p, d, 64);
    if (lane == 0) out_place[wid] = p + bp2[0];
    // fp8 pack of emb row (4 lanes -> 1 dword)
    float o1 = __shfl_down(o, 1, 64);
    float o2 = __shfl_down(o, 2, 64);
    float o3 = __shfl_down(o, 3, 64);
    int pk = __builtin_amdgcn_cvt_pk_fp8_f32(o, o1, 0, false);
    pk = __builtin_amdgcn_cvt_pk_fp8_f32(o2, o3, pk, true);
    if ((lane & 3) == 0)
        *(int*)(emb8 + (long)wid * EMBD + lane) = pk;
}

// ---- weight prep: fp8 transposed [n][k]; n: 0-63 We1, 64-191 Wa1, 192-255 Wa2(pad) ----
__global__ void k_prep(const float* __restrict__ We1, const float* __restrict__ Wa1,
                       const float* __restrict__ Wa2, unsigned char* __restrict__ Wt8) {
    int t = blockIdx.x * 256 + threadIdx.x;
    if (t >= 256 * 128) return;
    int n = t >> 7, k = t & 127;
    float v;
    if (n < 64)       v = We1[k * 64 + n];
    else if (n < 192) v = Wa1[k * 128 + (n - 64)];
    else { int n2 = n - 192; v = (n2 < MAXSEND) ? Wa2[k * MAXSEND + n2] : 0.f; }
    Wt8[t] = f2fp8(v);
}

// ---------------- action-edge MLP: fp8 MFMA, one 16-action m-tile per wave ----------------
__launch_bounds__(512, 4)
__global__ void k_action(const unsigned char* __restrict__ emb8, const int* __restrict__ ae,
                         const int* __restrict__ army, const unsigned char* __restrict__ Wt8,
                         const float* __restrict__ be1, const float* __restrict__ We2,
                         const float* __restrict__ be2, const float* __restrict__ ba1,
                         const float* __restrict__ ba2,
                         float* __restrict__ out_edge, float* __restrict__ out_army) {
    extern __shared__ char lds8[];
    int tid = threadIdx.x;
    // stage fp8 weights into padded LDS (256 rows x RSTR bytes)
    for (int i = tid; i < 2048; i += 512) {
        int rw = i >> 3, c16 = (i & 7) * 16;
        *(uint4*)(lds8 + rw * RSTR + c16) = *(const uint4*)(Wt8 + rw * 128 + c16);
    }
    __syncthreads();

    int w = tid >> 6, lane = tid & 63;
    int m = lane & 15, q = lane >> 4;                  // MFMA lane decomposition
    char* a1s = lds8 + 256 * RSTR + w * 16 * RSTR;     // per-wave 16xRSTR fp8 scratch

    float be1v[4], w2v[4], ba1v[8], ba2v[4];
#pragma unroll
    for (int t = 0; t < 4; t++) { be1v[t] = be1[t * 16 + m]; w2v[t] = We2[t * 16 + m]; }
#pragma unroll
    for (int t = 0; t < 8; t++) ba1v[t] = ba1[t * 16 + m];
#pragma unroll
    for (int nt = 0; nt < 4; nt++) { int n = nt * 16 + m; ba2v[nt] = (n < MAXSEND) ? ba2[n] : 0.f; }
    float be2v = be2[0];
    const f32x4 zero = {0.f, 0.f, 0.f, 0.f};

    int gw = blockIdx.x * 8 + w;
    int nwaves = gridDim.x * 8;
    for (int tile = gw; tile < NA / 16; tile += nwaves) {
        int a0 = tile * 16;
        // per-action (lane m holds action a0+m): src/tgt, armies, mask adjustment
        int2 st = ((const int2*)ae)[a0 + m];
        int army_s = army[st.x];
        int army_t = army[st.y];
        float adj_m = ((army_s <= 2) || (army_t >= 3 * army_s)) ? 1.f : 0.f;
        if (st.x == st.y) adj_m += 100.f;
        // A-fragments: lane holds EE[a0+m][kk*32 + q*8 ..+7] as fp8 bytes
        long af[4];
        af[0] = *(const long*)(emb8 + (long)st.x * EMBD + q * 8);
        af[1] = *(const long*)(emb8 + (long)st.x * EMBD + 32 + q * 8);
        af[2] = *(const long*)(emb8 + (long)st.y * EMBD + q * 8);
        af[3] = *(const long*)(emb8 + (long)st.y * EMBD + 32 + q * 8);
        // broadcast per-row (a = q*4+r) army/adj to all lanes
        float adjr[4]; int sar[4];
#pragma unroll
        for (int r = 0; r < 4; r++) {
            int rowlane = q * 4 + r;
            adjr[r] = __shfl(adj_m, rowlane, 64);
            sar[r]  = __shfl(army_s, rowlane, 64);
        }
        // stage 1: n-tiles 0..3 -> e1 (We1 rows), 4..11 -> a1 (Wa1 rows)
        f32x4 acc[12];
#pragma unroll
        for (int t = 0; t < 12; t++) acc[t] = zero;
#pragma unroll
        for (int t = 0; t < 12; t++) {
#pragma unroll
            for (int kk = 0; kk < 4; kk++) {
                long bfrag = *(const long*)(lds8 + (t * 16 + m) * RSTR + kk * 32 + q * 8);
                acc[t] = __builtin_amdgcn_mfma_f32_16x16x32_fp8_fp8(af[kk], bfrag, acc[t], 0, 0, 0);
            }
        }
        // e1 epilogue -> edge-logit partials (C layout: row a=q*4+r, col j=t*16+m)
        float elp[4] = {0.f, 0.f, 0.f, 0.f};
#pragma unroll
        for (int t = 0; t < 4; t++) {
#pragma unroll
            for (int r = 0; r < 4; r++) {
                float v = fmaxf(acc[t][r] + be1v[t], 0.f);
                elp[r] = fmaf(v, w2v[t], elp[r]);
            }
        }
        // a1 epilogue -> fp8 into per-wave LDS scratch
#pragma unroll
        for (int t = 4; t < 12; t++) {
#pragma unroll
            for (int r = 0; r < 4; r++) {
                float v = fmaxf(acc[t][r] + ba1v[t - 4], 0.f);
                a1s[(q * 4 + r) * RSTR + (t - 4) * 16 + m] = (char)f2fp8(v);
            }
        }
        // reduce edge logits over the 16 j-lanes in each quad
#pragma unroll
        for (int r = 0; r < 4; r++) {
            float s = elp[r];
            s += __shfl_xor(s, 1, 64);
            s += __shfl_xor(s, 2, 64);
            s += __shfl_xor(s, 4, 64);
            s += __shfl_xor(s, 8, 64);
            elp[r] = s;
        }
        if (m == 0) {
#pragma unroll
            for (int r = 0; r < 4; r++)
                out_edge[a0 + q * 4 + r] = elp[r] + be2v - adjr[r];
        }
        __asm__ volatile("s_waitcnt lgkmcnt(0)" ::: "memory");  // a1s writes -> reads
        // stage 2: army = relu(a1) @ Wa2 (rows 192..255 in LDS, cols padded to 64)
        long a2f[4];
#pragma unroll
        for (int kk = 0; kk < 4; kk++)
            a2f[kk] = *(const long*)(a1s + m * RSTR + kk * 32 + q * 8);
#pragma unroll
        for (int nt = 0; nt < 4; nt++) {
            f32x4 c2 = zero;
#pragma unroll
            for (int kk = 0; kk < 4; kk++) {
                long bfrag = *(const long*)(lds8 + (192 + nt * 16 + m) * RSTR + kk * 32 + q * 8);
                c2 = __builtin_amdgcn_mfma_f32_16x16x32_fp8_fp8(a2f[kk], bfrag, c2, 0, 0, 0);
            }
            int n = nt * 16 + m;
            if (n < MAXSEND) {
#pragma unroll
                for (int r = 0; r < 4; r++) {
                    int aa = a0 + q * 4 + r;
                    float v = c2[r] + ba2v[nt];
                    out_army[(long)aa * MAXSEND + n] = (n < sar[r]) ? v : -1e9f;
                }
            }
        }
    }
}

extern "C" void kernel_launch(void* const* d_in, const int* in_sizes, int n_in,
                              void* d_out, int out_size, void* d_ws, size_t ws_size,
                              hipStream_t stream) {
    const float* x    = (const float*)d_in[0];
    const int*   ei   = (const int*)d_in[1];
    const int*   ae   = (const int*)d_in[2];
    const int*   army = (const int*)d_in[3];
    const float* W1   = (const float*)d_in[4];
    const float* b1   = (const float*)d_in[5];
    const float* W2   = (const float*)d_in[6];
    const float* b2   = (const float*)d_in[7];
    const float* Wp1  = (const float*)d_in[8];
    const float* bp1  = (const float*)d_in[9];
    const float* Wp2  = (const float*)d_in[10];
    const float* bp2  = (const float*)d_in[11];
    const float* We1  = (const float*)d_in[12];
    const float* be1  = (const float*)d_in[13];
    const float* We2  = (const float*)d_in[14];
    const float* be2  = (const float*)d_in[15];
    const float* Wa1  = (const float*)d_in[16];
    const float* ba1  = (const float*)d_in[17];
    const float* Wa2  = (const float*)d_in[18];
    const float* ba2  = (const float*)d_in[19];
    float* out = (float*)d_out;

    char* ws = (char*)d_ws;
    int*           cnt    = (int*)ws;                         // 50000 ints
    float*         dinv   = (float*)(ws + 200000);            // 50000 f
    int*           off    = (int*)(ws + 400000);              // 50001 ints
    int*           cursor = (int*)(ws + 600064);              // 50000 ints
    int*           esrc   = (int*)(ws + 800064);              // 1.6M ints
    float*         A      = (float*)(ws + 7200064);           // 50000x64 f (Hs1)
    float*         B      = (float*)(ws + 20000064);          // 50000x64 f (Hs2)
    unsigned char* emb8   = (unsigned char*)(ws + 32800064);  // 50000x64 fp8
    unsigned char* Wt8    = (unsigned char*)(ws + 36000064);  // 256x128 fp8
    int*           bsum   = (int*)(ws + 36100064);            // 196 ints
    int*           boff   = (int*)(ws + 36101064);            // 196 ints

    // ---- CSR build (once per launch): count -> 3-stage parallel scan -> bucket ----
    hipMemsetAsync(cnt, 0, 200000, stream);
    k_count<<<6250, 256, 0, stream>>>(ei + NEDGE, cnt);
    k_scan1<<<NBLK, 256, 0, stream>>>(cnt, bsum);
    k_scan2<<<1, 256, 0, stream>>>(bsum, boff);
    k_scan3<<<NBLK, 256, 0, stream>>>(cnt, boff, off, cursor, dinv);
    k_bucket<<<6250, 256, 0, stream>>>(ei, ei + NEDGE, cursor, esrc);

    // ---- GCN layer 1 GEMM, then fused gather1+GEMM2, fused gather2+placement ----
    k_gemm_nodes<<<12500, 256, 0, stream>>>(x, W1, dinv, A);
    k_gather1<<<12500, 256, 0, stream>>>(A, off, esrc, dinv, b1, W2, B);
    k_gather2<<<12500, 256, 0, stream>>>(B, off, esrc, dinv, b2, Wp1, bp1, Wp2, bp2,
                                         out, emb8);

    // ---- action head (fp8 MFMA) ----
    k_prep<<<128, 256, 0, stream>>>(We1, Wa1, Wa2, Wt8);
    k_action<<<768, 512, 256 * RSTR + 8 * 16 * RSTR, stream>>>(
        emb8, ae, army, Wt8, be1, We2, be2, ba1, ba2, out + NN, out + NN + NA);
}